// Round 3
// baseline (637.302 us; speedup 1.0000x reference)
//
#include <hip/hip_runtime.h>

#define NROWS 8192
#define DDIM  1024           // elements per row (fp8: also bytes per row)
#define BM 256
#define BN 256
#define BKB 64               // K-bytes per K-tile (one 32x32x64 MFMA K-slab)
#define NKT (DDIM / BKB)     // 16 K-tiles
#define MARGIN_F 0.05f
#define FP8_SCALE 8.0f       // power of 2; sims are scaled by 64 in mining space

typedef __attribute__((ext_vector_type(8)))  int   int8v;
typedef __attribute__((ext_vector_type(4)))  int   int4v;
typedef __attribute__((ext_vector_type(16))) float floatx16;

__device__ __forceinline__ void g2lds16(const void* g, void* l) {
  __builtin_amdgcn_global_load_lds(
      (const __attribute__((address_space(1))) void*)g,
      (__attribute__((address_space(3))) void*)l, 16, 0, 0);
}

// Raw barrier: NO vmcnt drain (that's the whole point vs __syncthreads).
// Empty-asm memory clobbers pin compiler ds/global ops to this program point.
#define MEMFENCE() asm volatile("" ::: "memory")
#define SBAR()  do { MEMFENCE(); __builtin_amdgcn_s_barrier(); MEMFENCE(); } while (0)
#define LGKM0() do { asm volatile("s_waitcnt lgkmcnt(0)" ::: "memory"); \
                     __builtin_amdgcn_sched_barrier(0); } while (0)
#define VMC(n)  asm volatile("s_waitcnt vmcnt(" #n ")" ::: "memory")

// prep: 2048 blocks x 256 threads; wave w handles row 4*blockIdx + w.
// Exact fp32 pos_sim, fp32 -> fp8(e4m3, x8) quantize, zero keys + out.
__global__ void prep_kernel(const float* __restrict__ x, const float* __restrict__ y,
                            unsigned int* __restrict__ xq, unsigned int* __restrict__ yq,
                            float* __restrict__ pos, unsigned int* __restrict__ keys,
                            float* __restrict__ out) {
  const int t = threadIdx.x;
  const int lane = t & 63, wave = t >> 6;
  const int row = blockIdx.x * 4 + wave;
  const float4* xr = (const float4*)(x + (size_t)row * DDIM);
  const float4* yr = (const float4*)(y + (size_t)row * DDIM);
  unsigned int* xqr = xq + (size_t)row * 256;
  unsigned int* yqr = yq + (size_t)row * 256;
  float s = 0.f;
#pragma unroll
  for (int u = 0; u < 4; ++u) {
    const float4 a = xr[u * 64 + lane];
    const float4 b = yr[u * 64 + lane];
    s += a.x * b.x + a.y * b.y + a.z * b.z + a.w * b.w;
    int pa = __builtin_amdgcn_cvt_pk_fp8_f32(a.x * FP8_SCALE, a.y * FP8_SCALE, 0, false);
    pa     = __builtin_amdgcn_cvt_pk_fp8_f32(a.z * FP8_SCALE, a.w * FP8_SCALE, pa, true);
    int pb = __builtin_amdgcn_cvt_pk_fp8_f32(b.x * FP8_SCALE, b.y * FP8_SCALE, 0, false);
    pb     = __builtin_amdgcn_cvt_pk_fp8_f32(b.z * FP8_SCALE, b.w * FP8_SCALE, pb, true);
    xqr[u * 64 + lane] = (unsigned int)pa;
    yqr[u * 64 + lane] = (unsigned int)pb;
  }
  for (int m = 32; m; m >>= 1) s += __shfl_down(s, m, 64);
  if (lane == 0) { pos[row] = s; keys[row] = 0u; }
  if (blockIdx.x == 0 && t == 0) out[0] = 0.f;
}

// R11: 8-phase-style schedule (T3+T4+T2+T5) on a 256x256 tile, MX-fp8.
// R8 post-mortem arithmetic: MFMA 24%, LDS-port ~20%, staging ~12%, conflicts
// ~8% -- serialized by the 2-barrier loop (m233's structural stall). Catalog:
// counted-vmcnt phase schedule is the prerequisite for T2/T5 to pay.
// Structure: 512 thr = 8 waves (4M x 2N), wave tile 64x128 (R8's proven
// acc/key/epilogue). K-tile = 64 B; 4 LDS buffers (128 KB), staging pipeline
// depth 3 (stage kt+3 while computing kt). Per K-tile, 2 phases:
//   {ds_read 8|4 b128 ; 2 x global_load_lds ; s_barrier ; lgkmcnt(0) ;
//    setprio(1) ; 4 MFMA ; setprio(0) ; [vmcnt(8) at K-tile end] ; s_barrier}
// vmcnt(8) = 2 tiles x 4 issues in flight; tail 4 -> 0; never drained cold.
// LDS swizzle: chunk c of row r stored at c ^ ((r>>1)&3). Read side (lane
// r31,kh reads chunks 2kh,2kh+1 of row base+r31): banks spread 8 lanes per
// 4-bank group for lo AND hi reads -> true port minimum (old scheme had a
// measured ~4cyc/read tax). Carried by the global source address; LDS dest
// of global_load_lds stays linear (HW requirement).
__global__ __launch_bounds__(512, 2) void mine_kernel(
    const unsigned char* __restrict__ xq, const unsigned char* __restrict__ yq,
    const float* __restrict__ pos, unsigned int* __restrict__ keys) {
  // [buf 0..3][A=0,B=1][16 KB]
  __shared__ unsigned char smem[4][2][BM * BKB];
  __shared__ float pos_s[BM];

  const int t = threadIdx.x;
  // Bijective XCD swizzle: xcd = bid%8 owns nid in [128*xcd, 128*xcd+128):
  // 4 consecutive row-panels (1 MB of A, L2-resident) x all 32 col-blocks.
  const int bid = blockIdx.x;
  const int nid = (bid & 7) * 128 + (bid >> 3);
  const int rowBase = (nid >> 5) * BM;
  const int colBase = (nid & 31) * BN;

  if (t < BM) pos_s[t] = pos[rowBase + t] * (FP8_SCALE * FP8_SCALE);

  const int lane = t & 63;
  const int wave = t >> 6;
  const int wr = wave >> 1, wc = wave & 1;   // 4M x 2N, wave tile 64 x 128
  const int r31 = lane & 31, kh = lane >> 5;

  // ds_read offsets (swizzled). Row bases are multiples of 32 -> swizzle term
  // depends only on r31.
  const int fragSw = ((2 * kh) ^ ((r31 >> 1) & 3)) << 4;
  const int offA0 = (64 * wr + r31) * BKB + fragSw;    // + mi*32*BKB
  const int offB0 = (128 * wc + r31) * BKB + fragSw;   // + ni*32*BKB

  // Stage-side addressing: slot l = i*512 + t (16B units); row r = l>>2,
  // stored pos p = l&3 -> source chunk c = p ^ ((r>>1)&3). For both i=0,1:
  // c = (t&3) ^ ((t>>3)&3); rows t>>2 and 128+(t>>2).
  const int sr = t >> 2;
  const int sc = ((t & 3) ^ ((t >> 3) & 3)) * 16;
  const unsigned char* aSrc0 = xq + (size_t)(rowBase + sr) * DDIM + sc;
  const unsigned char* aSrc1 = xq + (size_t)(rowBase + 128 + sr) * DDIM + sc;
  const unsigned char* bSrc0 = yq + (size_t)(colBase + sr) * DDIM + sc;
  const unsigned char* bSrc1 = yq + (size_t)(colBase + 128 + sr) * DDIM + sc;
  const int dstOff0 = (wave * 64) * 16;          // + lane*16 added by HW
  const int dstOff1 = (512 + wave * 64) * 16;

#define STAGE_A(j) do {                                                        \
    g2lds16(aSrc0 + (j) * BKB, &smem[(j) & 3][0][dstOff0]);                    \
    g2lds16(aSrc1 + (j) * BKB, &smem[(j) & 3][0][dstOff1]);                    \
  } while (0)
#define STAGE_B(j) do {                                                        \
    g2lds16(bSrc0 + (j) * BKB, &smem[(j) & 3][1][dstOff0]);                    \
    g2lds16(bSrc1 + (j) * BKB, &smem[(j) & 3][1][dstOff1]);                    \
  } while (0)

  unsigned int key[2][16];
#pragma unroll
  for (int mi = 0; mi < 2; ++mi)
#pragma unroll
    for (int reg = 0; reg < 16; ++reg) key[mi][reg] = 0u;

  floatx16 acc[2][4];
#pragma unroll
  for (int mi = 0; mi < 2; ++mi)
#pragma unroll
    for (int ni = 0; ni < 4; ++ni)
#pragma unroll
      for (int r = 0; r < 16; ++r) acc[mi][ni][r] = 0.f;

  // Prologue: stage K-tiles 0,1,2 (12 issues/thread, program order = age).
  STAGE_A(0); STAGE_B(0);
  STAGE_A(1); STAGE_B(1);
  STAGE_A(2); STAGE_B(2);
  VMC(8);   // oldest 4 (K-tile 0) landed
  SBAR();   // ...for every wave's issues -> tile 0 fully in LDS

#pragma unroll
  for (int kt = 0; kt < NKT; ++kt) {
    const unsigned char* Ab = &smem[kt & 3][0][0];
    const unsigned char* Bb = &smem[kt & 3][1][0];

    // ---- Phase A: read af0,af1,bf0,bf1 ; stage A(kt+3) ; MFMA ni 0,1 ----
    int8v af[2];
#pragma unroll
    for (int mi = 0; mi < 2; ++mi) {
      const int oA = offA0 + mi * 32 * BKB;
      int4v lo = *(const int4v*)&Ab[oA];
      int4v hi = *(const int4v*)&Ab[oA ^ 16];
      af[mi] = __builtin_shufflevector(lo, hi, 0, 1, 2, 3, 4, 5, 6, 7);
    }
    int8v bf01[2];
#pragma unroll
    for (int ni = 0; ni < 2; ++ni) {
      const int oB = offB0 + ni * 32 * BKB;
      int4v lo = *(const int4v*)&Bb[oB];
      int4v hi = *(const int4v*)&Bb[oB ^ 16];
      bf01[ni] = __builtin_shufflevector(lo, hi, 0, 1, 2, 3, 4, 5, 6, 7);
    }
    if (kt < NKT - 3) STAGE_A(kt + 3);
    SBAR();
    LGKM0();
    __builtin_amdgcn_s_setprio(1);
#pragma unroll
    for (int ni = 0; ni < 2; ++ni) {
      acc[0][ni] = __builtin_amdgcn_mfma_scale_f32_32x32x64_f8f6f4(
          af[0], bf01[ni], acc[0][ni], 0, 0, 0, 0x7F7F7F7F, 0, 0x7F7F7F7F);
      acc[1][ni] = __builtin_amdgcn_mfma_scale_f32_32x32x64_f8f6f4(
          af[1], bf01[ni], acc[1][ni], 0, 0, 0, 0x7F7F7F7F, 0, 0x7F7F7F7F);
    }
    __builtin_amdgcn_s_setprio(0);
    SBAR();

    // ---- Phase B: read bf2,bf3 ; stage B(kt+3) ; MFMA ni 2,3 ; vmcnt ----
    int8v bf23[2];
#pragma unroll
    for (int ni = 0; ni < 2; ++ni) {
      const int oB = offB0 + (2 + ni) * 32 * BKB;
      int4v lo = *(const int4v*)&Bb[oB];
      int4v hi = *(const int4v*)&Bb[oB ^ 16];
      bf23[ni] = __builtin_shufflevector(lo, hi, 0, 1, 2, 3, 4, 5, 6, 7);
    }
    if (kt < NKT - 3) STAGE_B(kt + 3);
    SBAR();
    LGKM0();
    __builtin_amdgcn_s_setprio(1);
#pragma unroll
    for (int ni = 0; ni < 2; ++ni) {
      acc[0][2 + ni] = __builtin_amdgcn_mfma_scale_f32_32x32x64_f8f6f4(
          af[0], bf23[ni], acc[0][2 + ni], 0, 0, 0, 0x7F7F7F7F, 0, 0x7F7F7F7F);
      acc[1][2 + ni] = __builtin_amdgcn_mfma_scale_f32_32x32x64_f8f6f4(
          af[1], bf23[ni], acc[1][2 + ni], 0, 0, 0, 0x7F7F7F7F, 0, 0x7F7F7F7F);
    }
    __builtin_amdgcn_s_setprio(0);
    // Counted guard for next K-tile's reads: never drain to 0 mid-loop.
    if (kt < NKT - 3)      { VMC(8); }   // kt+2, kt+3 in flight
    else if (kt == NKT - 3){ VMC(4); }   // only kt+3==15 in flight
    else if (kt == NKT - 2){ VMC(0); }   // nothing new staged; drain last
    SBAR();
  }

  // Key fold (pure VALU). 32x32 C/D layout (HW-verified): col = lane&31,
  // row = (reg&3) + 8*(reg>>2) + 4*(lane>>5).
  int colv[4];
#pragma unroll
  for (int ni = 0; ni < 4; ++ni) colv[ni] = colBase + 128 * wc + 32 * ni + r31;
#pragma unroll
  for (int mi = 0; mi < 2; ++mi) {
#pragma unroll
    for (int reg = 0; reg < 16; ++reg) {
      const int row_l = 64 * wr + 32 * mi + (reg & 3) + 8 * (reg >> 2) + 4 * kh;
      const int row_g = rowBase + row_l;
      const float p = pos_s[row_l];
      unsigned int kk = key[mi][reg];
#pragma unroll
      for (int ni = 0; ni < 4; ++ni) {
        const float v = acc[mi][ni][reg];
        const bool dead = (colv[ni] == row_g) || (v > p);
        unsigned int u = __float_as_uint(v);
        u ^= (unsigned int)(((int)u) >> 31) | 0x80000000u;
        unsigned int kc = (u & 0xFFFFE000u) | (unsigned int)(8191 - colv[ni]);
        kc = dead ? 0u : kc;
        kk = kk > kc ? kk : kc;
      }
      key[mi][reg] = kk;
    }
  }

  // One butterfly + one atomic per owned (row, wc) — atomicMax merges wc pair.
#pragma unroll
  for (int mi = 0; mi < 2; ++mi) {
#pragma unroll
    for (int reg = 0; reg < 16; ++reg) {
      unsigned int kk = key[mi][reg];
#pragma unroll
      for (int m = 1; m <= 16; m <<= 1) {
        unsigned int o = __shfl_xor(kk, m, 64);
        kk = kk > o ? kk : o;
      }
      if (r31 == 0) {
        const int row_l = 64 * wr + 32 * mi + (reg & 3) + 8 * (reg >> 2) + 4 * kh;
        atomicMax(&keys[rowBase + row_l], kk);
      }
    }
  }
#undef STAGE_A
#undef STAGE_B
}

// Exact fp32 recompute of neg_sim for the mined index + loss reduction.
// 1024 blocks -> ample wave parallelism for the latency-bound gather.
__global__ void final_kernel(const float* __restrict__ x, const float* __restrict__ y,
                             const float* __restrict__ pos,
                             const unsigned int* __restrict__ keys,
                             float* __restrict__ out) {
  const int t = threadIdx.x;
  const int lane = t & 63, wave = t >> 6;
  float accl = 0.f;
#pragma unroll
  for (int i = 0; i < 2; ++i) {
    const int row = blockIdx.x * 8 + i * 4 + wave;
    const unsigned int k = keys[row];
    const int j = (k == 0u) ? 0 : (8191 - (int)(k & 8191u));  // all-masked -> argmax 0
    const float4* xr = (const float4*)(x + (size_t)row * DDIM);
    const float4* yr = (const float4*)(y + (size_t)j * DDIM);
    float s = 0.f;
#pragma unroll
    for (int u = 0; u < 4; ++u) {
      const float4 a = xr[lane + 64 * u];
      const float4 b = yr[lane + 64 * u];
      s += a.x * b.x + a.y * b.y + a.z * b.z + a.w * b.w;
    }
    for (int m = 32; m; m >>= 1) s += __shfl_down(s, m, 64);
    if (lane == 0) {
      const float l = MARGIN_F - pos[row] + s;
      accl += l > 0.f ? l : 0.f;
    }
  }
  __shared__ float ps[4];
  if (lane == 0) ps[wave] = accl;
  __syncthreads();
  if (t == 0) atomicAdd(out, (ps[0] + ps[1] + ps[2] + ps[3]) * (1.0f / (float)NROWS));
}

extern "C" void kernel_launch(void* const* d_in, const int* in_sizes, int n_in,
                              void* d_out, int out_size, void* d_ws, size_t ws_size,
                              hipStream_t stream) {
  const float* x = (const float*)d_in[0];
  const float* y = (const float*)d_in[1];
  float* out = (float*)d_out;

  // ws layout: keys 32 KB | pos 32 KB | xq 8 MB | yq 8 MB
  unsigned int* keys = (unsigned int*)d_ws;
  float* pos = (float*)((char*)d_ws + (size_t)NROWS * 4);
  unsigned char* xq = (unsigned char*)d_ws + (size_t)NROWS * 8;
  unsigned char* yq = xq + (size_t)NROWS * DDIM;

  prep_kernel<<<NROWS / 4, 256, 0, stream>>>(x, y, (unsigned int*)xq, (unsigned int*)yq,
                                             pos, keys, out);
  mine_kernel<<<(NROWS / BM) * (NROWS / BN), 512, 0, stream>>>(xq, yq, pos, keys);
  final_kernel<<<NROWS / 8, 256, 0, stream>>>(x, y, pos, keys, out);
}

// Round 4
// 321.613 us; speedup vs baseline: 1.9816x; 1.9816x over previous
//
#include <hip/hip_runtime.h>

#define NROWS 8192
#define DDIM  1024           // elements per row (fp8: also bytes per row)
#define BM 128
#define BN 128
#define BKB 128              // K-bytes per tile iteration
#define NSTRIPES 8
#define CT_PER_STRIPE 8      // 8 stripes x 8 ct x 128 cols = 8192
#define MARGIN_F 0.05f
#define FP8_SCALE 8.0f       // power of 2; sims are scaled by 64 in mining space

typedef __attribute__((ext_vector_type(8)))  int   int8v;
typedef __attribute__((ext_vector_type(4)))  int   int4v;
typedef __attribute__((ext_vector_type(16))) float floatx16;

__device__ __forceinline__ void g2lds16(const void* g, void* l) {
  __builtin_amdgcn_global_load_lds(
      (const __attribute__((address_space(1))) void*)g,
      (__attribute__((address_space(3))) void*)l, 16, 0, 0);
}

// prep: 2048 blocks x 256 threads; wave w handles row 4*blockIdx + w.
// Exact fp32 pos_sim, fp32 -> fp8(e4m3, x8) quantize, zero keys + out.
__global__ void prep_kernel(const float* __restrict__ x, const float* __restrict__ y,
                            unsigned int* __restrict__ xq, unsigned int* __restrict__ yq,
                            float* __restrict__ pos, unsigned int* __restrict__ keys,
                            float* __restrict__ out) {
  const int t = threadIdx.x;
  const int lane = t & 63, wave = t >> 6;
  const int row = blockIdx.x * 4 + wave;
  const float4* xr = (const float4*)(x + (size_t)row * DDIM);
  const float4* yr = (const float4*)(y + (size_t)row * DDIM);
  unsigned int* xqr = xq + (size_t)row * 256;
  unsigned int* yqr = yq + (size_t)row * 256;
  float s = 0.f;
#pragma unroll
  for (int u = 0; u < 4; ++u) {
    const float4 a = xr[u * 64 + lane];
    const float4 b = yr[u * 64 + lane];
    s += a.x * b.x + a.y * b.y + a.z * b.z + a.w * b.w;
    int pa = __builtin_amdgcn_cvt_pk_fp8_f32(a.x * FP8_SCALE, a.y * FP8_SCALE, 0, false);
    pa     = __builtin_amdgcn_cvt_pk_fp8_f32(a.z * FP8_SCALE, a.w * FP8_SCALE, pa, true);
    int pb = __builtin_amdgcn_cvt_pk_fp8_f32(b.x * FP8_SCALE, b.y * FP8_SCALE, 0, false);
    pb     = __builtin_amdgcn_cvt_pk_fp8_f32(b.z * FP8_SCALE, b.w * FP8_SCALE, pb, true);
    xqr[u * 64 + lane] = (unsigned int)pa;
    yqr[u * 64 + lane] = (unsigned int)pb;
  }
  for (int m = 32; m; m >>= 1) s += __shfl_down(s, m, 64);
  if (lane == 0) { pos[row] = s; keys[row] = 0u; }
  if (blockIdx.x == 0 && t == 0) out[0] = 0.f;
}

// R12: m148-recipe occupancy fix, spill-safe.
// Post-mortem R10/R11: WRITE_SIZE (31MB/186MB/1.07GB at R8/R10/R11) exposed
// accumulator SCRATCH SPILLS whenever demand exceeded the waves-per-EU reg
// split; R10 additionally paid 262MB A-refetch from the 32-stripe grid.
// R12 keeps R10's proven-correct compute geometry (128x128 tile, 4 waves,
// wave tile 64x64, acc[2][2]=64 regs, 2-barrier __syncthreads loop, R7
// staging+swizzle) but:
//  - stripes back to 8, CT=8 -> A-refetch 64MB; ~whole grid co-resident,
//    per-XCD working set A 1MB + B stream -> FETCH expected <= R8's 101MB.
//  - register diet to fit 3 waves/EU (arch<=84 + acc in AGPR): single
//    per-lane staging offset (sw=(t&7)^((t>>3)&7) is i-independent; row and
//    buffer terms are wave-uniform -> SGPR), inline col recompute, minimal
//    live temps. Tripwire: WRITE_SIZE >100MB means it spilled anyway.
__global__ __launch_bounds__(256, 3) void mine_kernel(
    const unsigned char* __restrict__ xq, const unsigned char* __restrict__ yq,
    const float* __restrict__ pos, unsigned int* __restrict__ keys) {
  __shared__ unsigned char As[BM * BKB];  // 16 KB, XOR-swizzled
  __shared__ unsigned char Bs[BN * BKB];  // 16 KB, XOR-swizzled
  __shared__ float pos_s[BM];

  const int t = threadIdx.x;
  const int rowBase = blockIdx.x * BM;
  const int stripe  = blockIdx.y;
  if (t < BM) pos_s[t] = pos[rowBase + t] * (FP8_SCALE * FP8_SCALE);

  const int lane = t & 63;
  const int wave = t >> 6;
  const int wr = wave >> 1, wc = wave & 1;   // 2x2 waves, wave tile 64x64
  const int r31 = lane & 31, kh = lane >> 5;

  const int fragOff = ((2 * kh) ^ (r31 & 7)) << 4;
  const int offA0 = (64 * wr + r31) * BKB + fragOff;   // + mi*32*BKB
  const int offB0 = (64 * wc + r31) * BKB + fragOff;   // + ni*32*BKB

  // Staging: slot c = i*256 + t; row r = c>>3 = i*32 + (t>>3); chunk
  // sw = (c&7)^(r&7) = (t&7)^((t>>3)&7)  (i*32 == 0 mod 8 -> i-independent).
  // Per-lane byte offset within a panel: (t>>3)*1024 + sw*16 (one VGPR);
  // +i*32768 and +k0 are wave-uniform (SGPR side).
  const int stageOff = (t >> 3) * DDIM + (((t & 7) ^ ((t >> 3) & 7)) << 4);
  const int ldsDst   = (wave * 64) * 16;   // + lane*16 added by HW

  unsigned int key[2][16];
#pragma unroll
  for (int mi = 0; mi < 2; ++mi)
#pragma unroll
    for (int reg = 0; reg < 16; ++reg) key[mi][reg] = 0u;

  for (int ct = 0; ct < CT_PER_STRIPE; ++ct) {
    const int colBase = stripe * (BN * CT_PER_STRIPE) + ct * BN;
    const unsigned char* aPan = xq + (size_t)rowBase * DDIM;
    const unsigned char* bPan = yq + (size_t)colBase * DDIM;

    floatx16 acc[2][2];
#pragma unroll
    for (int mi = 0; mi < 2; ++mi)
#pragma unroll
      for (int ni = 0; ni < 2; ++ni)
#pragma unroll
        for (int r = 0; r < 16; ++r) acc[mi][ni][r] = 0.f;

    for (int k0 = 0; k0 < DDIM; k0 += BKB) {
      __syncthreads();  // previous iteration's ds_reads done before overwrite
#pragma unroll
      for (int i = 0; i < 4; ++i)
        g2lds16(aPan + (i * 32 * DDIM + k0) + stageOff, &As[(i * 256) * 16 + ldsDst]);
#pragma unroll
      for (int i = 0; i < 4; ++i)
        g2lds16(bPan + (i * 32 * DDIM + k0) + stageOff, &Bs[(i * 256) * 16 + ldsDst]);
      __syncthreads();

#pragma unroll
      for (int ks = 0; ks < 2; ++ks) {
        const int kx = ks << 6;  // ^64 selects the second K-64 of the tile
        int8v af[2];
#pragma unroll
        for (int mi = 0; mi < 2; ++mi) {
          const int oA = (offA0 + mi * 32 * BKB) ^ kx;
          int4v lo = *(const int4v*)&As[oA];
          int4v hi = *(const int4v*)&As[oA ^ 16];
          af[mi] = __builtin_shufflevector(lo, hi, 0, 1, 2, 3, 4, 5, 6, 7);
        }
#pragma unroll
        for (int ni = 0; ni < 2; ++ni) {
          const int oB = (offB0 + ni * 32 * BKB) ^ kx;
          int4v blo = *(const int4v*)&Bs[oB];
          int4v bhi = *(const int4v*)&Bs[oB ^ 16];
          int8v bf = __builtin_shufflevector(blo, bhi, 0, 1, 2, 3, 4, 5, 6, 7);
          acc[0][ni] = __builtin_amdgcn_mfma_scale_f32_32x32x64_f8f6f4(
              af[0], bf, acc[0][ni], 0, 0, 0, 0x7F7F7F7F, 0, 0x7F7F7F7F);
          acc[1][ni] = __builtin_amdgcn_mfma_scale_f32_32x32x64_f8f6f4(
              af[1], bf, acc[1][ni], 0, 0, 0, 0x7F7F7F7F, 0, 0x7F7F7F7F);
        }
      }
    }

    // Per-ct key update (pure VALU; no shuffles, no atomics).
    // 32x32 C/D layout (HW-verified): col = lane&31,
    // row = (reg&3) + 8*(reg>>2) + 4*(lane>>5).
#pragma unroll
    for (int mi = 0; mi < 2; ++mi) {
#pragma unroll
      for (int reg = 0; reg < 16; ++reg) {
        const int row_l = 64 * wr + 32 * mi + (reg & 3) + 8 * (reg >> 2) + 4 * kh;
        const int row_g = rowBase + row_l;
        const float p = pos_s[row_l];
        unsigned int kk = key[mi][reg];
#pragma unroll
        for (int ni = 0; ni < 2; ++ni) {
          const int col = colBase + 64 * wc + 32 * ni + r31;
          const float v = acc[mi][ni][reg];
          const bool dead = (col == row_g) || (v > p);
          unsigned int u = __float_as_uint(v);
          u ^= (unsigned int)(((int)u) >> 31) | 0x80000000u;
          unsigned int kc = (u & 0xFFFFE000u) | (unsigned int)(8191 - col);
          kc = dead ? 0u : kc;
          kk = kk > kc ? kk : kc;
        }
        key[mi][reg] = kk;
      }
    }
  }

  // One butterfly + one atomic per owned row.
#pragma unroll
  for (int mi = 0; mi < 2; ++mi) {
#pragma unroll
    for (int reg = 0; reg < 16; ++reg) {
      unsigned int kk = key[mi][reg];
#pragma unroll
      for (int m = 1; m <= 16; m <<= 1) {
        unsigned int o = __shfl_xor(kk, m, 64);
        kk = kk > o ? kk : o;
      }
      if (r31 == 0) {
        const int row_l = 64 * wr + 32 * mi + (reg & 3) + 8 * (reg >> 2) + 4 * kh;
        atomicMax(&keys[rowBase + row_l], kk);
      }
    }
  }
}

// Exact fp32 recompute of neg_sim for the mined index + loss reduction.
// 1024 blocks -> ample wave parallelism for the latency-bound gather.
__global__ void final_kernel(const float* __restrict__ x, const float* __restrict__ y,
                             const float* __restrict__ pos,
                             const unsigned int* __restrict__ keys,
                             float* __restrict__ out) {
  const int t = threadIdx.x;
  const int lane = t & 63, wave = t >> 6;
  float accl = 0.f;
#pragma unroll
  for (int i = 0; i < 2; ++i) {
    const int row = blockIdx.x * 8 + i * 4 + wave;
    const unsigned int k = keys[row];
    const int j = (k == 0u) ? 0 : (8191 - (int)(k & 8191u));  // all-masked -> argmax 0
    const float4* xr = (const float4*)(x + (size_t)row * DDIM);
    const float4* yr = (const float4*)(y + (size_t)j * DDIM);
    float s = 0.f;
#pragma unroll
    for (int u = 0; u < 4; ++u) {
      const float4 a = xr[lane + 64 * u];
      const float4 b = yr[lane + 64 * u];
      s += a.x * b.x + a.y * b.y + a.z * b.z + a.w * b.w;
    }
    for (int m = 32; m; m >>= 1) s += __shfl_down(s, m, 64);
    if (lane == 0) {
      const float l = MARGIN_F - pos[row] + s;
      accl += l > 0.f ? l : 0.f;
    }
  }
  __shared__ float ps[4];
  if (lane == 0) ps[wave] = accl;
  __syncthreads();
  if (t == 0) atomicAdd(out, (ps[0] + ps[1] + ps[2] + ps[3]) * (1.0f / (float)NROWS));
}

extern "C" void kernel_launch(void* const* d_in, const int* in_sizes, int n_in,
                              void* d_out, int out_size, void* d_ws, size_t ws_size,
                              hipStream_t stream) {
  const float* x = (const float*)d_in[0];
  const float* y = (const float*)d_in[1];
  float* out = (float*)d_out;

  // ws layout: keys 32 KB | pos 32 KB | xq 8 MB | yq 8 MB
  unsigned int* keys = (unsigned int*)d_ws;
  float* pos = (float*)((char*)d_ws + (size_t)NROWS * 4);
  unsigned char* xq = (unsigned char*)d_ws + (size_t)NROWS * 8;
  unsigned char* yq = xq + (size_t)NROWS * DDIM;

  prep_kernel<<<NROWS / 4, 256, 0, stream>>>(x, y, (unsigned int*)xq, (unsigned int*)yq,
                                             pos, keys, out);
  dim3 grid(NROWS / BM, NSTRIPES);
  mine_kernel<<<grid, 256, 0, stream>>>(xq, yq, pos, keys);
  final_kernel<<<NROWS / 8, 256, 0, stream>>>(x, y, pos, keys, out);
}